// Round 1
// baseline (63.760 us; speedup 1.0000x reference)
//
#include <hip/hip_runtime.h>

// Problem constants (from reference):
//   feature_map: (B=16, H=27, W=48, C=512) fp32
//   nmses:       (B=16, R=100, 4) fp32  -> (cx, cy, w, h) in pixels
//   output:      (B, R, 7, 7, C) fp32
#define BB   16
#define RR   100
#define HH   27
#define WW   48
#define CC   512
#define PP   7

// float4 units
#define C4       (CC / 4)            // 128 float4 per (b,y,x) row
#define ROW4     (WW * C4)           // 6144  float4 per (b,y)
#define IMG4     (HH * ROW4)         // 165888 float4 per b

// total float4 work items: B*R*49*128 = 10,035,200
#define TOTAL4   (BB * RR * PP * PP * C4)

__global__ __launch_bounds__(256) void roi_crop_resize_kernel(
    const float* __restrict__ fm,
    const float* __restrict__ nms,
    float* __restrict__ out)
{
    int idx = blockIdx.x * 256 + threadIdx.x;
    if (idx >= TOTAL4) return;

    const int c4   = idx & (C4 - 1);     // which float4 within the channel dim
    const int cell = idx >> 7;           // (b*R + r)*49 + py*7 + px

    const int px = cell % PP;
    int t        = cell / PP;
    const int py = t % PP;
    t           /= PP;                   // t = b*R + r
    const int b  = t / RR;

    // Load box (cx, cy, w, h); nms is (B*R, 4) contiguous fp32 -> float4 aligned.
    const float4 box = ((const float4*)nms)[t];
    const float cx = box.x, cy = box.y, w = box.z, h = box.w;

    // Normalized corners, matching reference op order (true divisions).
    const float x1 = (cx - w * 0.5f) / 768.0f;
    const float x2 = (cx + w * 0.5f) / 768.0f;
    const float y1 = (cy - h * 0.5f) / 432.0f;
    const float y2 = (cy + h * 0.5f) / 432.0f;

    // Sample coordinates:
    //   ys = y1*(H-1) + py*(y2-y1)*(H-1)/(P-1)
    const float pyf = (float)py;
    const float pxf = (float)px;
    const float ys = y1 * 26.0f + pyf * (y2 - y1) * 26.0f / 6.0f;
    const float xs = x1 * 47.0f + pxf * (x2 - x1) * 47.0f / 6.0f;

    const bool valid = (ys >= 0.0f) && (ys <= 26.0f) &&
                       (xs >= 0.0f) && (xs <= 47.0f);

    float4 o;
    if (valid) {   // wave-uniform: each wave's 64 lanes share one cell
        const float y0f = floorf(ys);
        const float x0f = floorf(xs);
        const float ly = ys - y0f;
        const float lx = xs - x0f;

        int y0 = (int)y0f; y0 = min(max(y0, 0), HH - 1);
        const int y1i = min(y0 + 1, HH - 1);
        int x0 = (int)x0f; x0 = min(max(x0, 0), WW - 1);
        const int x1i = min(x0 + 1, WW - 1);

        const float4* f4  = (const float4*)fm;
        const float4* img = f4 + (size_t)b * IMG4;
        const float4* rT  = img + y0  * ROW4;
        const float4* rB  = img + y1i * ROW4;

        const float4 tl = rT[x0  * C4 + c4];
        const float4 tr = rT[x1i * C4 + c4];
        const float4 bl = rB[x0  * C4 + c4];
        const float4 br = rB[x1i * C4 + c4];

        // top = tl + (tr-tl)*lx; bot = bl + (br-bl)*lx; out = top + (bot-top)*ly
        float4 top, bot;
        top.x = tl.x + (tr.x - tl.x) * lx;
        top.y = tl.y + (tr.y - tl.y) * lx;
        top.z = tl.z + (tr.z - tl.z) * lx;
        top.w = tl.w + (tr.w - tl.w) * lx;
        bot.x = bl.x + (br.x - bl.x) * lx;
        bot.y = bl.y + (br.y - bl.y) * lx;
        bot.z = bl.z + (br.z - bl.z) * lx;
        bot.w = bl.w + (br.w - bl.w) * lx;
        o.x = top.x + (bot.x - top.x) * ly;
        o.y = top.y + (bot.y - top.y) * ly;
        o.z = top.z + (bot.z - top.z) * ly;
        o.w = top.w + (bot.w - top.w) * ly;
    } else {
        o.x = 0.0f; o.y = 0.0f; o.z = 0.0f; o.w = 0.0f;
    }

    ((float4*)out)[idx] = o;
}

extern "C" void kernel_launch(void* const* d_in, const int* in_sizes, int n_in,
                              void* d_out, int out_size, void* d_ws, size_t ws_size,
                              hipStream_t stream)
{
    const float* fm  = (const float*)d_in[0];   // (16,27,48,512) fp32
    const float* nms = (const float*)d_in[1];   // (16,100,4) fp32
    float* out = (float*)d_out;                 // (16,100,7,7,512) fp32

    const int threads = 256;
    const int blocks  = (TOTAL4 + threads - 1) / threads;   // 39200
    roi_crop_resize_kernel<<<blocks, threads, 0, stream>>>(fm, nms, out);
}

// Round 3
// 47.168 us; speedup vs baseline: 1.3518x; 1.3518x over previous
//
#include <hip/hip_runtime.h>

// Problem constants (from reference):
//   feature_map: (B=16, H=27, W=48, C=512) fp32
//   nmses:       (B=16, R=100, 4) fp32  -> (cx, cy, w, h) in pixels
//   output:      (B, R, 7, 7, C) fp32
#define BB   16
#define RR   100
#define HH   27
#define WW   48
#define CC   512
#define PP   7

// float4 units
#define C4       (CC / 4)            // 128 float4 per (b,y,x) pixel
#define ROW4     (WW * C4)           // 6144  float4 per (b,y)
#define IMG4     (HH * ROW4)         // 165888 float4 per b

// total float4 work items: B*R*49*128 = 10,035,200
#define TOTAL4   (BB * RR * PP * PP * C4)
#define NBLOCKS  (TOTAL4 / 256)      // 39200, exact (no tail)
#define NXCD     8

// True vector type (HIP's float4 is a class; nontemporal builtin rejects it).
typedef float vf4 __attribute__((ext_vector_type(4)));

__global__ __launch_bounds__(256) void roi_crop_resize_kernel(
    const float* __restrict__ fm,
    const float* __restrict__ nms,
    float* __restrict__ out)
{
    // XCD-aware bijective swizzle: hardware assigns block bid to XCD (bid % 8).
    // Remap so each XCD owns a CONTIGUOUS chunk of the work space -> the
    // ~24.5 blocks of one box (which share ~128 KB of feature rows) stay on
    // one XCD's private L2. NBLOCKS % 8 == 0 so the simple form is bijective.
    const int bid  = blockIdx.x;
    const int wgid = (bid % NXCD) * (NBLOCKS / NXCD) + bid / NXCD;

    const int idx = wgid * 256 + threadIdx.x;

    const int c4   = idx & (C4 - 1);     // which float4 within the channel dim
    const int cell = idx >> 7;           // (b*R + r)*49 + py*7 + px

    const int px = cell % PP;
    int t        = cell / PP;
    const int py = t % PP;
    t           /= PP;                   // t = b*R + r
    const int b  = t / RR;

    // Load box (cx, cy, w, h); nms is (B*R, 4) contiguous fp32 -> 16B aligned.
    const vf4 box = ((const vf4*)nms)[t];
    const float cx = box.x, cy = box.y, w = box.z, h = box.w;

    // Normalized corners, matching reference op order (true divisions).
    const float x1 = (cx - w * 0.5f) / 768.0f;
    const float x2 = (cx + w * 0.5f) / 768.0f;
    const float y1 = (cy - h * 0.5f) / 432.0f;
    const float y2 = (cy + h * 0.5f) / 432.0f;

    // Sample coordinates:
    //   ys = y1*(H-1) + py*(y2-y1)*(H-1)/(P-1)
    const float pyf = (float)py;
    const float pxf = (float)px;
    const float ys = y1 * 26.0f + pyf * (y2 - y1) * 26.0f / 6.0f;
    const float xs = x1 * 47.0f + pxf * (x2 - x1) * 47.0f / 6.0f;

    const bool valid = (ys >= 0.0f) && (ys <= 26.0f) &&
                       (xs >= 0.0f) && (xs <= 47.0f);

    vf4 o;
    if (valid) {   // wave-uniform: each wave's 64 lanes share one cell
        const float y0f = floorf(ys);
        const float x0f = floorf(xs);
        const float ly = ys - y0f;
        const float lx = xs - x0f;

        int y0 = (int)y0f; y0 = min(max(y0, 0), HH - 1);
        const int y1i = min(y0 + 1, HH - 1);
        int x0 = (int)x0f; x0 = min(max(x0, 0), WW - 1);
        const int x1i = min(x0 + 1, WW - 1);

        const vf4* img = ((const vf4*)fm) + (size_t)b * IMG4;
        const vf4* rT  = img + y0  * ROW4;
        const vf4* rB  = img + y1i * ROW4;

        const vf4 tl = rT[x0  * C4 + c4];
        const vf4 tr = rT[x1i * C4 + c4];
        const vf4 bl = rB[x0  * C4 + c4];
        const vf4 br = rB[x1i * C4 + c4];

        // top = tl + (tr-tl)*lx; bot = bl + (br-bl)*lx; out = top + (bot-top)*ly
        const vf4 top = tl + (tr - tl) * lx;
        const vf4 bot = bl + (br - bl) * lx;
        o = top + (bot - top) * ly;
    } else {
        o = (vf4)(0.0f);
    }

    // Output is write-once, never re-read by us: nontemporal store keeps the
    // 160 MB stream from evicting the 42.5 MB feature map out of L2.
    __builtin_nontemporal_store(o, ((vf4*)out) + idx);
}

extern "C" void kernel_launch(void* const* d_in, const int* in_sizes, int n_in,
                              void* d_out, int out_size, void* d_ws, size_t ws_size,
                              hipStream_t stream)
{
    const float* fm  = (const float*)d_in[0];   // (16,27,48,512) fp32
    const float* nms = (const float*)d_in[1];   // (16,100,4) fp32
    float* out = (float*)d_out;                 // (16,100,7,7,512) fp32

    roi_crop_resize_kernel<<<NBLOCKS, 256, 0, stream>>>(fm, nms, out);
}

// Round 4
// 37.579 us; speedup vs baseline: 1.6967x; 1.2552x over previous
//
#include <hip/hip_runtime.h>

// feature_map: (B=16, H=27, W=48, C=512) fp32
// nmses:       (B=16, R=100, 4) fp32  (cx, cy, w, h in pixels)
// output:      (B, R, 7, 7, C) fp32
#define BB   16
#define RR   100
#define HH   27
#define WW   48
#define CC   512
#define PP   7

#define C4       (CC / 4)            // 128 float4 per pixel
#define ROW4     (WW * C4)           // 6144 float4 per (b,y)
#define IMG4     (HH * ROW4)         // 165888 float4 per b

#define TOTAL4   (BB * RR * PP * PP * C4)   // 10,035,200 float4
#define NTHREADS (TOTAL4 / 2)               // 2 float4 per thread
#define NBLOCKS  (NTHREADS / 256)           // 19600; 19600 % 8 == 0
#define NXCD     8

typedef float vf4 __attribute__((ext_vector_type(4)));

__global__ __launch_bounds__(256) void roi_crop_resize_kernel(
    const float* __restrict__ fm,
    const float* __restrict__ nms,
    float* __restrict__ out)
{
    // XCD-aware bijective swizzle (NBLOCKS % 8 == 0): each XCD gets a
    // contiguous box range -> its ~1-image working set stays in its 4MB L2.
    const int bid  = blockIdx.x;
    const int wgid = (bid % NXCD) * (NBLOCKS / NXCD) + bid / NXCD;

    const int idx  = wgid * 256 + threadIdx.x;   // [0, NTHREADS)
    const int c4   = idx & 63;                   // lane's first float4 slot
    const int cell = idx >> 6;                   // one wave == one cell

    const int px = cell % PP;
    int t        = cell / PP;
    const int py = t % PP;
    t           /= PP;                           // t = b*R + r  (wave-uniform)

    // Hoist the wave-uniform box index to an SGPR -> scalar (SMEM) box load
    // instead of 64 redundant per-lane VMEM loads.
    const int ts = __builtin_amdgcn_readfirstlane(t);
    const int b  = ts / RR;

    const vf4 box = ((const vf4*)nms)[ts];
    const float cx = box.x, cy = box.y, w = box.z, h = box.w;

    // Normalized corners, reference op order (true divisions).
    const float x1 = (cx - w * 0.5f) / 768.0f;
    const float x2 = (cx + w * 0.5f) / 768.0f;
    const float y1 = (cy - h * 0.5f) / 432.0f;
    const float y2 = (cy + h * 0.5f) / 432.0f;

    const float ys = y1 * 26.0f + (float)py * (y2 - y1) * 26.0f / 6.0f;
    const float xs = x1 * 47.0f + (float)px * (x2 - x1) * 47.0f / 6.0f;

    const bool valid = (ys >= 0.0f) && (ys <= 26.0f) &&
                       (xs >= 0.0f) && (xs <= 47.0f);

    vf4 o0, o1;
    if (valid) {   // wave-uniform branch
        const float y0f = floorf(ys);
        const float x0f = floorf(xs);
        const float ly = ys - y0f;
        const float lx = xs - x0f;

        int y0 = (int)y0f; y0 = min(max(y0, 0), HH - 1);
        const int y1i = min(y0 + 1, HH - 1);
        int x0 = (int)x0f; x0 = min(max(x0, 0), WW - 1);
        const int x1i = min(x0 + 1, WW - 1);

        const vf4* img = ((const vf4*)fm) + (size_t)b * IMG4;
        const vf4* rT  = img + y0  * ROW4;
        const vf4* rB  = img + y1i * ROW4;

        // 8 independent 16B loads -> deep MLP per wave.
        const vf4 tl0 = rT[x0  * C4 + c4];
        const vf4 tr0 = rT[x1i * C4 + c4];
        const vf4 bl0 = rB[x0  * C4 + c4];
        const vf4 br0 = rB[x1i * C4 + c4];
        const vf4 tl1 = rT[x0  * C4 + c4 + 64];
        const vf4 tr1 = rT[x1i * C4 + c4 + 64];
        const vf4 bl1 = rB[x0  * C4 + c4 + 64];
        const vf4 br1 = rB[x1i * C4 + c4 + 64];

        const vf4 top0 = tl0 + (tr0 - tl0) * lx;
        const vf4 bot0 = bl0 + (br0 - bl0) * lx;
        o0 = top0 + (bot0 - top0) * ly;
        const vf4 top1 = tl1 + (tr1 - tl1) * lx;
        const vf4 bot1 = bl1 + (br1 - bl1) * lx;
        o1 = top1 + (bot1 - top1) * ly;
    } else {
        o0 = (vf4)(0.0f);
        o1 = (vf4)(0.0f);
    }

    // Two coalesced 1KB wave bursts; nontemporal (write-once stream).
    vf4* op = ((vf4*)out) + (size_t)cell * C4 + c4;
    __builtin_nontemporal_store(o0, op);
    __builtin_nontemporal_store(o1, op + 64);
}

extern "C" void kernel_launch(void* const* d_in, const int* in_sizes, int n_in,
                              void* d_out, int out_size, void* d_ws, size_t ws_size,
                              hipStream_t stream)
{
    const float* fm  = (const float*)d_in[0];
    const float* nms = (const float*)d_in[1];
    float* out = (float*)d_out;

    roi_crop_resize_kernel<<<NBLOCKS, 256, 0, stream>>>(fm, nms, out);
}

// Round 5
// 37.562 us; speedup vs baseline: 1.6975x; 1.0005x over previous
//
#include <hip/hip_runtime.h>

// feature_map: (B=16, H=27, W=48, C=512) fp32
// nmses:       (B=16, R=100, 4) fp32  (cx, cy, w, h in pixels)
// output:      (B, R, 7, 7, C) fp32
#define BB   16
#define RR   100
#define HH   27
#define WW   48
#define CC   512
#define PP   7

#define C4       (CC / 4)            // 128 float4 per pixel
#define ROW4     (WW * C4)           // 6144 float4 per (b,y)
#define IMG4     (HH * ROW4)         // 165888 float4 per b

#define TOTAL4   (BB * RR * PP * PP * C4)   // 10,035,200 float4
#define NTHREADS (TOTAL4 / 4)               // 4 float4 per thread
#define NBLOCKS  (NTHREADS / 256)           // 9800; 9800 % 8 == 0
#define NXCD     8

typedef float vf4 __attribute__((ext_vector_type(4)));

// Per-cell sampling state (all wave-uniform / scalar).
struct CellS {
    const vf4* rT;
    const vf4* rB;
    int xo0, xo1;        // x0*C4, x1i*C4
    float lx, ly;
    bool valid;
};

__device__ __forceinline__ CellS cell_setup(const float* __restrict__ fm,
                                            const float* __restrict__ nms,
                                            int cell)
{
    CellS s;
    const int px = cell % PP;
    int t        = cell / PP;
    const int py = t % PP;
    t           /= PP;

    const int ts = __builtin_amdgcn_readfirstlane(t);
    const int b  = ts / RR;

    const vf4 box = ((const vf4*)nms)[ts];
    const float cx = box.x, cy = box.y, w = box.z, h = box.w;

    const float x1 = (cx - w * 0.5f) / 768.0f;
    const float x2 = (cx + w * 0.5f) / 768.0f;
    const float y1 = (cy - h * 0.5f) / 432.0f;
    const float y2 = (cy + h * 0.5f) / 432.0f;

    const float ys = y1 * 26.0f + (float)py * (y2 - y1) * 26.0f / 6.0f;
    const float xs = x1 * 47.0f + (float)px * (x2 - x1) * 47.0f / 6.0f;

    s.valid = (ys >= 0.0f) && (ys <= 26.0f) &&
              (xs >= 0.0f) && (xs <= 47.0f);

    const float y0f = floorf(ys);
    const float x0f = floorf(xs);
    s.ly = ys - y0f;
    s.lx = xs - x0f;

    int y0 = (int)y0f; y0 = min(max(y0, 0), HH - 1);
    const int y1i = min(y0 + 1, HH - 1);
    int x0 = (int)x0f; x0 = min(max(x0, 0), WW - 1);
    const int x1i = min(x0 + 1, WW - 1);

    const vf4* img = ((const vf4*)fm) + (size_t)b * IMG4;
    s.rT  = img + y0  * ROW4;
    s.rB  = img + y1i * ROW4;
    s.xo0 = x0  * C4;
    s.xo1 = x1i * C4;
    return s;
}

__global__ __launch_bounds__(256) void roi_crop_resize_kernel(
    const float* __restrict__ fm,
    const float* __restrict__ nms,
    float* __restrict__ out)
{
    // XCD-aware bijective swizzle (NBLOCKS % 8 == 0): contiguous box ranges
    // per XCD keep each XCD's ~2.65MB image slice in its private 4MB L2.
    const int bid  = blockIdx.x;
    const int wgid = (bid % NXCD) * (NBLOCKS / NXCD) + bid / NXCD;

    const int idx   = wgid * 256 + threadIdx.x;  // [0, NTHREADS)
    const int c4    = idx & 63;                  // lane's float4 slot
    const int pair  = idx >> 6;                  // wave handles 2 cells
    const int cell0 = pair * 2;
    const int cell1 = cell0 + 1;

    const CellS s0 = cell_setup(fm, nms, cell0);
    const CellS s1 = cell_setup(fm, nms, cell1);

    // Issue all 16 independent 16B loads before any use (deep MLP).
    vf4 a_tl0, a_tr0, a_bl0, a_br0, a_tl1, a_tr1, a_bl1, a_br1;
    vf4 b_tl0, b_tr0, b_bl0, b_br0, b_tl1, b_tr1, b_bl1, b_br1;

    if (s0.valid) {
        a_tl0 = s0.rT[s0.xo0 + c4];      a_tr0 = s0.rT[s0.xo1 + c4];
        a_bl0 = s0.rB[s0.xo0 + c4];      a_br0 = s0.rB[s0.xo1 + c4];
        a_tl1 = s0.rT[s0.xo0 + c4 + 64]; a_tr1 = s0.rT[s0.xo1 + c4 + 64];
        a_bl1 = s0.rB[s0.xo0 + c4 + 64]; a_br1 = s0.rB[s0.xo1 + c4 + 64];
    }
    if (s1.valid) {
        b_tl0 = s1.rT[s1.xo0 + c4];      b_tr0 = s1.rT[s1.xo1 + c4];
        b_bl0 = s1.rB[s1.xo0 + c4];      b_br0 = s1.rB[s1.xo1 + c4];
        b_tl1 = s1.rT[s1.xo0 + c4 + 64]; b_tr1 = s1.rT[s1.xo1 + c4 + 64];
        b_bl1 = s1.rB[s1.xo0 + c4 + 64]; b_br1 = s1.rB[s1.xo1 + c4 + 64];
    }

    vf4 o00, o01, o10, o11;
    if (s0.valid) {
        const vf4 top0 = a_tl0 + (a_tr0 - a_tl0) * s0.lx;
        const vf4 bot0 = a_bl0 + (a_br0 - a_bl0) * s0.lx;
        o00 = top0 + (bot0 - top0) * s0.ly;
        const vf4 top1 = a_tl1 + (a_tr1 - a_tl1) * s0.lx;
        const vf4 bot1 = a_bl1 + (a_br1 - a_bl1) * s0.lx;
        o01 = top1 + (bot1 - top1) * s0.ly;
    } else {
        o00 = (vf4)(0.0f); o01 = (vf4)(0.0f);
    }
    if (s1.valid) {
        const vf4 top0 = b_tl0 + (b_tr0 - b_tl0) * s1.lx;
        const vf4 bot0 = b_bl0 + (b_br0 - b_bl0) * s1.lx;
        o10 = top0 + (bot0 - top0) * s1.ly;
        const vf4 top1 = b_tl1 + (b_tr1 - b_tl1) * s1.lx;
        const vf4 bot1 = b_bl1 + (b_br1 - b_bl1) * s1.lx;
        o11 = top1 + (bot1 - top1) * s1.ly;
    } else {
        o10 = (vf4)(0.0f); o11 = (vf4)(0.0f);
    }

    // 4KB contiguous burst per wave (cells are adjacent in output).
    vf4* op = ((vf4*)out) + (size_t)cell0 * C4 + c4;
    __builtin_nontemporal_store(o00, op);
    __builtin_nontemporal_store(o01, op + 64);
    __builtin_nontemporal_store(o10, op + 128);
    __builtin_nontemporal_store(o11, op + 192);
}

extern "C" void kernel_launch(void* const* d_in, const int* in_sizes, int n_in,
                              void* d_out, int out_size, void* d_ws, size_t ws_size,
                              hipStream_t stream)
{
    const float* fm  = (const float*)d_in[0];
    const float* nms = (const float*)d_in[1];
    float* out = (float*)d_out;

    roi_crop_resize_kernel<<<NBLOCKS, 256, 0, stream>>>(fm, nms, out);
}